// Round 16
// baseline (44.446 us; speedup 1.0000x reference)
//
#include <hip/hip_runtime.h>
#include <math.h>
#include <limits.h>

#define LL 2048
#define PP (LL*3)
#define FPB 8
#define NP 8

// -------- device-global scratch (rewritten every call) --------
__device__ int   g_firstj[LL];
__device__ int   g_cnt[LL];
__device__ int   g_ii[LL];
__device__ int   g_jj[LL];
__device__ int   g_K;
// folded frame records, 12 floats = 48 B: [M(9) | d(3)]; diff = p - M*t - d
// term0: frames [0, LL); term1: frames [LL, LL + LL + K)
__device__ __align__(16) float g_frames[(3*LL)*12];
// packed point records, 8 floats = 32 B: [p.xyz | t.xyz | pad pad]
__device__ __align__(16) float g_pts[PP*8];
__device__ double g_sum[2];

// rigid_from_3points for one residue: x = 9 floats (x1,x2,x3 rows)
__device__ inline void rigid3(const float* x, float* rot, float* tran) {
  float x1x=x[0],x1y=x[1],x1z=x[2];
  float x2x=x[3],x2y=x[4],x2z=x[5];
  float x3x=x[6],x3y=x[7],x3z=x[8];
  float v1x=x3x-x2x, v1y=x3y-x2y, v1z=x3z-x2z;
  float v2x=x1x-x2x, v2y=x1y-x2y, v2z=x1z-x2z;
  float n1 = sqrtf(v1x*v1x+v1y*v1y+v1z*v1z) + 0.001f;
  float e1x=v1x/n1, e1y=v1y/n1, e1z=v1z/n1;
  float dd = e1x*v2x+e1y*v2y+e1z*v2z;
  float u2x=v2x-e1x*dd, u2y=v2y-e1y*dd, u2z=v2z-e1z*dd;
  float n2 = sqrtf(u2x*u2x+u2y*u2y+u2z*u2z) + 1e-8f;
  float e2x=u2x/n2, e2y=u2y/n2, e2z=u2z/n2;
  rot[0]=e1x; rot[1]=e1y; rot[2]=e1z;
  rot[3]=e2x; rot[4]=e2y; rot[5]=e2z;
  rot[6]=e1y*e2z - e1z*e2y;
  rot[7]=e1z*e2x - e1x*e2z;
  rot[8]=e1x*e2y - e1y*e2x;
  tran[0]=x2x; tran[1]=x2y; tran[2]=x2z;
}

// folded record: M = A^T * B, d = tp - M*tt   (A=R_pred rows, B=R_true rows)
__device__ inline void packfr12(float* fr, const float* A, const float* tp,
                                const float* B, const float* tt) {
  float M[9];
  #pragma unroll
  for (int i = 0; i < 3; ++i)
    #pragma unroll
    for (int j = 0; j < 3; ++j)
      M[i*3+j] = A[0+i]*B[0+j] + A[3+i]*B[3+j] + A[6+i]*B[6+j];
  #pragma unroll
  for (int i = 0; i < 9; ++i) fr[i] = M[i];
  #pragma unroll
  for (int i = 0; i < 3; ++i)
    fr[9+i] = tp[i] - (M[i*3]*tt[0] + M[i*3+1]*tt[1] + M[i*3+2]*tt[2]);
}

// blocks [0,LL): per-row matrix scan (first j>i with m!=0); below-diagonal
// int4 groups are skipped entirely (exec-masked loads -> ~half the HBM reads)
// blocks [LL, LL+8): term0 folded frames
// blocks [LL+8, LL+8+24): packed point records
__global__ void __launch_bounds__(256) k_prep(const int4* __restrict__ m4,
                                              const float* __restrict__ coor,
                                              const float* __restrict__ target,
                                              const float* __restrict__ prot,
                                              const float* __restrict__ ptran) {
  int bid = blockIdx.x;
  int t = threadIdx.x;
  if (bid < LL) {
    int i = bid;                        // row
    const int4* row = m4 + (size_t)i*512;   // 2048 cols = 512 int4
    int j0 = t*8;
    int best = INT_MAX;
    if (j0 + 7 > i) {                   // group contains some j > i
      int4 a = row[2*t], b = row[2*t+1];
      if (a.x && (j0   > i)) best = j0;
      if (a.y && (j0+1 > i)) best = min(best, j0+1);
      if (a.z && (j0+2 > i)) best = min(best, j0+2);
      if (a.w && (j0+3 > i)) best = min(best, j0+3);
      if (b.x && (j0+4 > i)) best = min(best, j0+4);
      if (b.y && (j0+5 > i)) best = min(best, j0+5);
      if (b.z && (j0+6 > i)) best = min(best, j0+6);
      if (b.w && (j0+7 > i)) best = min(best, j0+7);
    }
    for (int o = 32; o >= 1; o >>= 1) best = min(best, __shfl_xor(best, o));
    __shared__ int wmin[4];
    int lane = t & 63, wid = t >> 6;
    if (lane == 0) wmin[wid] = best;
    __syncthreads();
    if (t == 0)
      g_firstj[i] = min(min(wmin[0], wmin[1]), min(wmin[2], wmin[3]));
  } else if (bid < LL + 8) {
    int f = (bid - LL)*256 + t;
    if (f == 0) { g_sum[0] = 0.0; g_sum[1] = 0.0; }
    if (f >= LL) return;
    float B[9], tt[3];
    rigid3(target + f*9, B, tt);
    float A[9], tp[3];
    #pragma unroll
    for (int i = 0; i < 9; ++i) A[i] = prot[f*9+i];
    #pragma unroll
    for (int i = 0; i < 3; ++i) tp[i] = ptran[f*3+i];
    packfr12(g_frames + f*12, A, tp, B, tt);
  } else {
    int p = (bid - LL - 8)*256 + t;     // p < 6144
    float4* o4 = reinterpret_cast<float4*>(g_pts);
    o4[p*2+0] = make_float4(coor[p*3], coor[p*3+1], coor[p*3+2], target[p*3]);
    o4[p*2+1] = make_float4(target[p*3+1], target[p*3+2], 0.f, 0.f);
  }
}

// single block: exclusive prefix-sum of "row has pair", build ii/jj, K
__global__ void __launch_bounds__(1024) k_scan() {
  int t = threadIdx.x;
  int r0 = 2*t, r1 = 2*t+1;
  int f0 = g_firstj[r0], f1 = g_firstj[r1];
  int h0 = (f0 != INT_MAX) ? 1 : 0;
  int h1 = (f1 != INT_MAX) ? 1 : 0;
  int local = h0 + h1;
  int lane = t & 63;
  int wid  = t >> 6;                 // 16 waves
  int incl = local;
  for (int o = 1; o < 64; o <<= 1) {
    int v = __shfl_up(incl, o);
    if (lane >= o) incl += v;
  }
  __shared__ int wsum[16];
  if (lane == 63) wsum[wid] = incl;
  __syncthreads();
  if (t < 16) {
    int iv = wsum[t];
    for (int o = 1; o < 16; o <<= 1) {
      int u = __shfl_up(iv, o);
      if (t >= o) iv += u;
    }
    wsum[t] = iv;
  }
  __syncthreads();
  int waveoff = (wid == 0) ? 0 : wsum[wid-1];
  int excl = waveoff + incl - local;   // pairs among rows < r0
  g_cnt[r0] = excl;
  g_cnt[r1] = excl + h0;
  if (h0) { g_ii[excl]      = r0; g_jj[excl]      = f0; }
  if (h1) { g_ii[excl + h0] = r1; g_jj[excl + h0] = f1; }
  if (t == 1023) g_K = waveoff + incl;
}

// term1 folded frame records computed directly from coords (no aug buffers)
__global__ void k_augfr(const float* __restrict__ coor,
                        const float* __restrict__ target) {
  int idx = blockIdx.x*blockDim.x + threadIdx.x;
  float xp[9], xt[9];
  int pos;
  if (idx < LL) {
    pos = idx + g_cnt[idx];
    #pragma unroll
    for (int c = 0; c < 9; ++c) { xp[c] = coor[idx*9+c]; xt[c] = target[idx*9+c]; }
  } else {
    int k = idx - LL;
    if (k >= g_K) return;
    int a = g_ii[k], b = g_jj[k];
    pos = a + k + 1;
    #pragma unroll
    for (int c = 0; c < 9; ++c) {
      xp[c] = 0.5f*(coor[a*9+c]   + coor[b*9+c]);
      xt[c] = 0.5f*(target[a*9+c] + target[b*9+c]);
    }
  }
  float A[9], tp[3], B[9], tt[3];
  rigid3(xp, A, tp);
  rigid3(xt, B, tt);
  packfr12(g_frames + (size_t)(LL + pos)*12, A, tp, B, tt);
}

// fused FAPE — R7 structure (measured best), FPB 16->8: doubles the wave count
// (3456 -> 6912 waves, ~6.75/SIMD avg) to hide the per-unroll-2 s_load drain.
// NP=8 points/thread in VGPRs, frames via wave-uniform float4 loads
// (-> s_load, SGPRs), #pragma unroll 2, launch_bounds(256,4). No fused
// finalize (R14 lesson: threadfence+done-atomic tail costs ~5-7 us).
__global__ void __launch_bounds__(256, 4) k_fape() {
  int Ftot = 2*LL + g_K;
  int f0 = blockIdx.y * FPB;
  if (f0 >= Ftot) return;
  int nf = min(FPB, Ftot - f0);
  int term1 = (f0 >= LL) ? 1 : 0;
  float clampv = term1 ? 5.f : 40.f;
  int t = threadIdx.x;

  int pbase = blockIdx.x*(256*NP) + t;   // grid.x * 256 * NP == PP exactly
  const float4* pt4 = reinterpret_cast<const float4*>(g_pts);
  float px[NP], py[NP], pz[NP], ttx[NP], tty[NP], ttz[NP];
  #pragma unroll
  for (int k = 0; k < NP; ++k) {
    int p = pbase + k*256;
    float4 a = pt4[p*2+0];
    float4 b = pt4[p*2+1];
    px[k] = a.x; py[k] = a.y; pz[k] = a.z;
    ttx[k] = a.w; tty[k] = b.x; ttz[k] = b.y;
  }
  float acc = 0.f;

  // wave-uniform frame pointer: compiler promotes to scalar loads (SGPRs)
  const float4* fr4 = reinterpret_cast<const float4*>(g_frames) + (size_t)f0*3;
  #pragma unroll 2
  for (int q = 0; q < nf; ++q) {
    float4 w0 = fr4[q*3+0];   // M00 M01 M02 M10
    float4 w1 = fr4[q*3+1];   // M11 M12 M20 M21
    float4 w2 = fr4[q*3+2];   // M22 d0  d1  d2
    #pragma unroll
    for (int k = 0; k < NP; ++k) {
      float m0 = fmaf(w0.x, ttx[k], fmaf(w0.y, tty[k], fmaf(w0.z, ttz[k], w2.y)));
      float m1 = fmaf(w0.w, ttx[k], fmaf(w1.x, tty[k], fmaf(w1.y, ttz[k], w2.z)));
      float m2 = fmaf(w1.z, ttx[k], fmaf(w1.w, tty[k], fmaf(w2.x, ttz[k], w2.w)));
      float dx = px[k] - m0, dy = py[k] - m1, dz = pz[k] - m2;
      float ss = fmaf(dx, dx, fmaf(dy, dy, fmaf(dz, dz, 0.001f)));
      acc += fminf(__builtin_amdgcn_sqrtf(ss), clampv);
    }
  }

  for (int o = 32; o >= 1; o >>= 1) acc += __shfl_down(acc, o);
  __shared__ float w[4];
  int lane = t & 63, wid = t >> 6;
  if (lane == 0) w[wid] = acc;
  __syncthreads();
  if (t == 0) {
    double s = (double)w[0] + (double)w[1] + (double)w[2] + (double)w[3];
    atomicAdd(&g_sum[term1], s);
  }
}

__global__ void k_final(float* __restrict__ out) {
  int K = g_K;
  double fape = g_sum[0] / ((double)LL * (double)PP);
  double r;
  if (K == 0) {
    r = fape / 10.0;
  } else {
    double fp = g_sum[1] / ((double)(LL + K) * (double)PP);
    r = (fape + fp) / 10.0;
  }
  out[0] = (float)r;
}

extern "C" void kernel_launch(void* const* d_in, const int* in_sizes, int n_in,
                              void* d_out, int out_size, void* d_ws, size_t ws_size,
                              hipStream_t stream) {
  const float* coor   = (const float*)d_in[0];
  const float* prot   = (const float*)d_in[1];
  const float* ptran  = (const float*)d_in[2];
  const float* target = (const float*)d_in[3];
  const int*   matrix = (const int*)d_in[4];
  float* out = (float*)d_out;

  k_prep<<<LL + 8 + PP/256, 256, 0, stream>>>((const int4*)matrix, coor, target, prot, ptran);
  k_scan<<<1, 1024, 0, stream>>>();
  k_augfr<<<16, 256, 0, stream>>>(coor, target);
  dim3 grid(PP/(256*NP), (3*LL)/FPB);   // 3 x 768 = 2304 blocks (1728 active)
  k_fape<<<grid, 256, 0, stream>>>();
  k_final<<<1, 1, 0, stream>>>(out);
}

// Round 17
// 38.247 us; speedup vs baseline: 1.1621x; 1.1621x over previous
//
#include <hip/hip_runtime.h>
#include <math.h>
#include <limits.h>

#define LL 2048
#define PP (LL*3)
#define FPB 16
#define NP 8

// -------- device-global scratch (rewritten every call) --------
__device__ int   g_firstj[LL];
__device__ int   g_cnt[LL];
__device__ int   g_ii[LL];
__device__ int   g_jj[LL];
__device__ int   g_K;
// folded frame records, 12 floats = 48 B: [M(9) | d(3)]; diff = p - M*t - d
// term0: frames [0, LL); term1: frames [LL, LL + LL + K)
__device__ __align__(16) float g_frames[(3*LL)*12];
// packed point records, 8 floats = 32 B: [p.xyz | t.xyz | pad pad]
__device__ __align__(16) float g_pts[PP*8];
__device__ double g_sum[2];

// rigid_from_3points for one residue: x = 9 floats (x1,x2,x3 rows)
__device__ inline void rigid3(const float* x, float* rot, float* tran) {
  float x1x=x[0],x1y=x[1],x1z=x[2];
  float x2x=x[3],x2y=x[4],x2z=x[5];
  float x3x=x[6],x3y=x[7],x3z=x[8];
  float v1x=x3x-x2x, v1y=x3y-x2y, v1z=x3z-x2z;
  float v2x=x1x-x2x, v2y=x1y-x2y, v2z=x1z-x2z;
  float n1 = sqrtf(v1x*v1x+v1y*v1y+v1z*v1z) + 0.001f;
  float e1x=v1x/n1, e1y=v1y/n1, e1z=v1z/n1;
  float dd = e1x*v2x+e1y*v2y+e1z*v2z;
  float u2x=v2x-e1x*dd, u2y=v2y-e1y*dd, u2z=v2z-e1z*dd;
  float n2 = sqrtf(u2x*u2x+u2y*u2y+u2z*u2z) + 1e-8f;
  float e2x=u2x/n2, e2y=u2y/n2, e2z=u2z/n2;
  rot[0]=e1x; rot[1]=e1y; rot[2]=e1z;
  rot[3]=e2x; rot[4]=e2y; rot[5]=e2z;
  rot[6]=e1y*e2z - e1z*e2y;
  rot[7]=e1z*e2x - e1x*e2z;
  rot[8]=e1x*e2y - e1y*e2x;
  tran[0]=x2x; tran[1]=x2y; tran[2]=x2z;
}

// folded record: M = A^T * B, d = tp - M*tt   (A=R_pred rows, B=R_true rows)
__device__ inline void packfr12(float* fr, const float* A, const float* tp,
                                const float* B, const float* tt) {
  float M[9];
  #pragma unroll
  for (int i = 0; i < 3; ++i)
    #pragma unroll
    for (int j = 0; j < 3; ++j)
      M[i*3+j] = A[0+i]*B[0+j] + A[3+i]*B[3+j] + A[6+i]*B[6+j];
  #pragma unroll
  for (int i = 0; i < 9; ++i) fr[i] = M[i];
  #pragma unroll
  for (int i = 0; i < 3; ++i)
    fr[9+i] = tp[i] - (M[i*3]*tt[0] + M[i*3+1]*tt[1] + M[i*3+2]*tt[2]);
}

// blocks [0,LL): per-row matrix scan (first j>i with m!=0); below-diagonal
// int4 groups skipped (exec-masked loads -> ~half the HBM reads)
// blocks [LL, LL+8): term0 folded frames
// blocks [LL+8, LL+8+24): packed point records
__global__ void __launch_bounds__(256) k_prep(const int4* __restrict__ m4,
                                              const float* __restrict__ coor,
                                              const float* __restrict__ target,
                                              const float* __restrict__ prot,
                                              const float* __restrict__ ptran) {
  int bid = blockIdx.x;
  int t = threadIdx.x;
  if (bid < LL) {
    int i = bid;                        // row
    const int4* row = m4 + (size_t)i*512;   // 2048 cols = 512 int4
    int j0 = t*8;
    int best = INT_MAX;
    if (j0 + 7 > i) {                   // group contains some j > i
      int4 a = row[2*t], b = row[2*t+1];
      if (a.x && (j0   > i)) best = j0;
      if (a.y && (j0+1 > i)) best = min(best, j0+1);
      if (a.z && (j0+2 > i)) best = min(best, j0+2);
      if (a.w && (j0+3 > i)) best = min(best, j0+3);
      if (b.x && (j0+4 > i)) best = min(best, j0+4);
      if (b.y && (j0+5 > i)) best = min(best, j0+5);
      if (b.z && (j0+6 > i)) best = min(best, j0+6);
      if (b.w && (j0+7 > i)) best = min(best, j0+7);
    }
    for (int o = 32; o >= 1; o >>= 1) best = min(best, __shfl_xor(best, o));
    __shared__ int wmin[4];
    int lane = t & 63, wid = t >> 6;
    if (lane == 0) wmin[wid] = best;
    __syncthreads();
    if (t == 0)
      g_firstj[i] = min(min(wmin[0], wmin[1]), min(wmin[2], wmin[3]));
  } else if (bid < LL + 8) {
    int f = (bid - LL)*256 + t;
    if (f == 0) { g_sum[0] = 0.0; g_sum[1] = 0.0; }
    if (f >= LL) return;
    float B[9], tt[3];
    rigid3(target + f*9, B, tt);
    float A[9], tp[3];
    #pragma unroll
    for (int i = 0; i < 9; ++i) A[i] = prot[f*9+i];
    #pragma unroll
    for (int i = 0; i < 3; ++i) tp[i] = ptran[f*3+i];
    packfr12(g_frames + f*12, A, tp, B, tt);
  } else {
    int p = (bid - LL - 8)*256 + t;     // p < 6144
    float4* o4 = reinterpret_cast<float4*>(g_pts);
    o4[p*2+0] = make_float4(coor[p*3], coor[p*3+1], coor[p*3+2], target[p*3]);
    o4[p*2+1] = make_float4(target[p*3+1], target[p*3+2], 0.f, 0.f);
  }
}

// single block: scan (prefix-sum, ii/jj, K), then the SAME block computes all
// term1 folded frame records (isolated fusion of k_augfr — saves one launch).
// __syncthreads() + same-CU write-through L1/L2 makes the scan's global
// writes visible to the aug phase within this block.
__global__ void __launch_bounds__(1024) k_scanaug(const float* __restrict__ coor,
                                                  const float* __restrict__ target) {
  int t = threadIdx.x;
  int r0 = 2*t, r1 = 2*t+1;
  int f0 = g_firstj[r0], f1 = g_firstj[r1];
  int h0 = (f0 != INT_MAX) ? 1 : 0;
  int h1 = (f1 != INT_MAX) ? 1 : 0;
  int local = h0 + h1;
  int lane = t & 63;
  int wid  = t >> 6;                 // 16 waves
  int incl = local;
  for (int o = 1; o < 64; o <<= 1) {
    int v = __shfl_up(incl, o);
    if (lane >= o) incl += v;
  }
  __shared__ int wsum[16];
  if (lane == 63) wsum[wid] = incl;
  __syncthreads();
  if (t < 16) {
    int iv = wsum[t];
    for (int o = 1; o < 16; o <<= 1) {
      int u = __shfl_up(iv, o);
      if (t >= o) iv += u;
    }
    wsum[t] = iv;
  }
  __syncthreads();
  int waveoff = (wid == 0) ? 0 : wsum[wid-1];
  int excl = waveoff + incl - local;   // pairs among rows < r0
  int c0 = excl, c1 = excl + h0;
  g_cnt[r0] = c0;
  g_cnt[r1] = c1;
  if (h0) { g_ii[excl]      = r0; g_jj[excl]      = f0; }
  if (h1) { g_ii[excl + h0] = r1; g_jj[excl + h0] = f1; }
  int Ktot = waveoff + incl;           // thread 1023 holds the total
  if (t == 1023) g_K = Ktot;
  __syncthreads();                     // scan writes visible block-wide

  int K = g_K;
  for (int idx = t; idx < LL + K; idx += 1024) {
    float xp[9], xt[9];
    int pos;
    if (idx < LL) {
      pos = idx + g_cnt[idx];
      #pragma unroll
      for (int c = 0; c < 9; ++c) { xp[c] = coor[idx*9+c]; xt[c] = target[idx*9+c]; }
    } else {
      int k = idx - LL;
      int a = g_ii[k], b = g_jj[k];
      pos = a + k + 1;
      #pragma unroll
      for (int c = 0; c < 9; ++c) {
        xp[c] = 0.5f*(coor[a*9+c]   + coor[b*9+c]);
        xt[c] = 0.5f*(target[a*9+c] + target[b*9+c]);
      }
    }
    float A[9], tp[3], B[9], tt[3];
    rigid3(xp, A, tp);
    rigid3(xt, B, tt);
    packfr12(g_frames + (size_t)(LL + pos)*12, A, tp, B, tt);
  }
}

// fused FAPE — EXACT R15/R7 kernel (measured best: 34.7 us total): NP=8
// points/thread in VGPRs, FPB=16 frames via wave-uniform global float4 loads
// (-> s_load, SGPRs), #pragma unroll 2, launch_bounds(256,4). No fused
// finalize (R14: threadfence+done-atomic tail costs ~5-7 us).
__global__ void __launch_bounds__(256, 4) k_fape() {
  int Ftot = 2*LL + g_K;
  int f0 = blockIdx.y * FPB;
  if (f0 >= Ftot) return;
  int nf = min(FPB, Ftot - f0);
  int term1 = (f0 >= LL) ? 1 : 0;
  float clampv = term1 ? 5.f : 40.f;
  int t = threadIdx.x;

  int pbase = blockIdx.x*(256*NP) + t;   // grid.x * 256 * NP == PP exactly
  const float4* pt4 = reinterpret_cast<const float4*>(g_pts);
  float px[NP], py[NP], pz[NP], ttx[NP], tty[NP], ttz[NP];
  #pragma unroll
  for (int k = 0; k < NP; ++k) {
    int p = pbase + k*256;
    float4 a = pt4[p*2+0];
    float4 b = pt4[p*2+1];
    px[k] = a.x; py[k] = a.y; pz[k] = a.z;
    ttx[k] = a.w; tty[k] = b.x; ttz[k] = b.y;
  }
  float acc = 0.f;

  // wave-uniform frame pointer: compiler promotes to scalar loads (SGPRs)
  const float4* fr4 = reinterpret_cast<const float4*>(g_frames) + (size_t)f0*3;
  #pragma unroll 2
  for (int q = 0; q < nf; ++q) {
    float4 w0 = fr4[q*3+0];   // M00 M01 M02 M10
    float4 w1 = fr4[q*3+1];   // M11 M12 M20 M21
    float4 w2 = fr4[q*3+2];   // M22 d0  d1  d2
    #pragma unroll
    for (int k = 0; k < NP; ++k) {
      float m0 = fmaf(w0.x, ttx[k], fmaf(w0.y, tty[k], fmaf(w0.z, ttz[k], w2.y)));
      float m1 = fmaf(w0.w, ttx[k], fmaf(w1.x, tty[k], fmaf(w1.y, ttz[k], w2.z)));
      float m2 = fmaf(w1.z, ttx[k], fmaf(w1.w, tty[k], fmaf(w2.x, ttz[k], w2.w)));
      float dx = px[k] - m0, dy = py[k] - m1, dz = pz[k] - m2;
      float ss = fmaf(dx, dx, fmaf(dy, dy, fmaf(dz, dz, 0.001f)));
      acc += fminf(__builtin_amdgcn_sqrtf(ss), clampv);
    }
  }

  for (int o = 32; o >= 1; o >>= 1) acc += __shfl_down(acc, o);
  __shared__ float w[4];
  int lane = t & 63, wid = t >> 6;
  if (lane == 0) w[wid] = acc;
  __syncthreads();
  if (t == 0) {
    double s = (double)w[0] + (double)w[1] + (double)w[2] + (double)w[3];
    atomicAdd(&g_sum[term1], s);
  }
}

__global__ void k_final(float* __restrict__ out) {
  int K = g_K;
  double fape = g_sum[0] / ((double)LL * (double)PP);
  double r;
  if (K == 0) {
    r = fape / 10.0;
  } else {
    double fp = g_sum[1] / ((double)(LL + K) * (double)PP);
    r = (fape + fp) / 10.0;
  }
  out[0] = (float)r;
}

extern "C" void kernel_launch(void* const* d_in, const int* in_sizes, int n_in,
                              void* d_out, int out_size, void* d_ws, size_t ws_size,
                              hipStream_t stream) {
  const float* coor   = (const float*)d_in[0];
  const float* prot   = (const float*)d_in[1];
  const float* ptran  = (const float*)d_in[2];
  const float* target = (const float*)d_in[3];
  const int*   matrix = (const int*)d_in[4];
  float* out = (float*)d_out;

  k_prep<<<LL + 8 + PP/256, 256, 0, stream>>>((const int4*)matrix, coor, target, prot, ptran);
  k_scanaug<<<1, 1024, 0, stream>>>(coor, target);
  dim3 grid(PP/(256*NP), (3*LL)/FPB);   // 3 x 384 = 1152 blocks (864 active)
  k_fape<<<grid, 256, 0, stream>>>();
  k_final<<<1, 1, 0, stream>>>(out);
}

// Round 18
// 34.709 us; speedup vs baseline: 1.2805x; 1.1019x over previous
//
#include <hip/hip_runtime.h>
#include <math.h>
#include <limits.h>

#define LL 2048
#define PP (LL*3)
#define FPB 16
#define NP 8

// -------- device-global scratch (rewritten every call) --------
__device__ int   g_firstj[LL];
__device__ int   g_cnt[LL];
__device__ int   g_ii[LL];
__device__ int   g_jj[LL];
__device__ int   g_K;
// folded frame records, 12 floats = 48 B: [M(9) | d(3)]; diff = p - M*t - d
// term0: frames [0, LL); term1: frames [LL, LL + LL + K)
__device__ __align__(16) float g_frames[(3*LL)*12];
// packed point records, 8 floats = 32 B: [p.xyz | t.xyz | pad pad]
__device__ __align__(16) float g_pts[PP*8];
__device__ double g_sum[2];

// rigid_from_3points for one residue: x = 9 floats (x1,x2,x3 rows)
__device__ inline void rigid3(const float* x, float* rot, float* tran) {
  float x1x=x[0],x1y=x[1],x1z=x[2];
  float x2x=x[3],x2y=x[4],x2z=x[5];
  float x3x=x[6],x3y=x[7],x3z=x[8];
  float v1x=x3x-x2x, v1y=x3y-x2y, v1z=x3z-x2z;
  float v2x=x1x-x2x, v2y=x1y-x2y, v2z=x1z-x2z;
  float n1 = sqrtf(v1x*v1x+v1y*v1y+v1z*v1z) + 0.001f;
  float e1x=v1x/n1, e1y=v1y/n1, e1z=v1z/n1;
  float dd = e1x*v2x+e1y*v2y+e1z*v2z;
  float u2x=v2x-e1x*dd, u2y=v2y-e1y*dd, u2z=v2z-e1z*dd;
  float n2 = sqrtf(u2x*u2x+u2y*u2y+u2z*u2z) + 1e-8f;
  float e2x=u2x/n2, e2y=u2y/n2, e2z=u2z/n2;
  rot[0]=e1x; rot[1]=e1y; rot[2]=e1z;
  rot[3]=e2x; rot[4]=e2y; rot[5]=e2z;
  rot[6]=e1y*e2z - e1z*e2y;
  rot[7]=e1z*e2x - e1x*e2z;
  rot[8]=e1x*e2y - e1y*e2x;
  tran[0]=x2x; tran[1]=x2y; tran[2]=x2z;
}

// folded record: M = A^T * B, d = tp - M*tt   (A=R_pred rows, B=R_true rows)
__device__ inline void packfr12(float* fr, const float* A, const float* tp,
                                const float* B, const float* tt) {
  float M[9];
  #pragma unroll
  for (int i = 0; i < 3; ++i)
    #pragma unroll
    for (int j = 0; j < 3; ++j)
      M[i*3+j] = A[0+i]*B[0+j] + A[3+i]*B[3+j] + A[6+i]*B[6+j];
  #pragma unroll
  for (int i = 0; i < 9; ++i) fr[i] = M[i];
  #pragma unroll
  for (int i = 0; i < 3; ++i)
    fr[9+i] = tp[i] - (M[i*3]*tt[0] + M[i*3+1]*tt[1] + M[i*3+2]*tt[2]);
}

// blocks [0,LL): per-row matrix scan (first j>i with m!=0); below-diagonal
// int4 groups skipped (exec-masked loads -> ~half the HBM reads)
// blocks [LL, LL+8): term0 folded frames
// blocks [LL+8, LL+8+24): packed point records
__global__ void __launch_bounds__(256) k_prep(const int4* __restrict__ m4,
                                              const float* __restrict__ coor,
                                              const float* __restrict__ target,
                                              const float* __restrict__ prot,
                                              const float* __restrict__ ptran) {
  int bid = blockIdx.x;
  int t = threadIdx.x;
  if (bid < LL) {
    int i = bid;                        // row
    const int4* row = m4 + (size_t)i*512;   // 2048 cols = 512 int4
    int j0 = t*8;
    int best = INT_MAX;
    if (j0 + 7 > i) {                   // group contains some j > i
      int4 a = row[2*t], b = row[2*t+1];
      if (a.x && (j0   > i)) best = j0;
      if (a.y && (j0+1 > i)) best = min(best, j0+1);
      if (a.z && (j0+2 > i)) best = min(best, j0+2);
      if (a.w && (j0+3 > i)) best = min(best, j0+3);
      if (b.x && (j0+4 > i)) best = min(best, j0+4);
      if (b.y && (j0+5 > i)) best = min(best, j0+5);
      if (b.z && (j0+6 > i)) best = min(best, j0+6);
      if (b.w && (j0+7 > i)) best = min(best, j0+7);
    }
    for (int o = 32; o >= 1; o >>= 1) best = min(best, __shfl_xor(best, o));
    __shared__ int wmin[4];
    int lane = t & 63, wid = t >> 6;
    if (lane == 0) wmin[wid] = best;
    __syncthreads();
    if (t == 0)
      g_firstj[i] = min(min(wmin[0], wmin[1]), min(wmin[2], wmin[3]));
  } else if (bid < LL + 8) {
    int f = (bid - LL)*256 + t;
    if (f == 0) { g_sum[0] = 0.0; g_sum[1] = 0.0; }
    if (f >= LL) return;
    float B[9], tt[3];
    rigid3(target + f*9, B, tt);
    float A[9], tp[3];
    #pragma unroll
    for (int i = 0; i < 9; ++i) A[i] = prot[f*9+i];
    #pragma unroll
    for (int i = 0; i < 3; ++i) tp[i] = ptran[f*3+i];
    packfr12(g_frames + f*12, A, tp, B, tt);
  } else {
    int p = (bid - LL - 8)*256 + t;     // p < 6144
    float4* o4 = reinterpret_cast<float4*>(g_pts);
    o4[p*2+0] = make_float4(coor[p*3], coor[p*3+1], coor[p*3+2], target[p*3]);
    o4[p*2+1] = make_float4(target[p*3+1], target[p*3+2], 0.f, 0.f);
  }
}

// single block: exclusive prefix-sum of "row has pair", build ii/jj, K
__global__ void __launch_bounds__(1024) k_scan() {
  int t = threadIdx.x;
  int r0 = 2*t, r1 = 2*t+1;
  int f0 = g_firstj[r0], f1 = g_firstj[r1];
  int h0 = (f0 != INT_MAX) ? 1 : 0;
  int h1 = (f1 != INT_MAX) ? 1 : 0;
  int local = h0 + h1;
  int lane = t & 63;
  int wid  = t >> 6;                 // 16 waves
  int incl = local;
  for (int o = 1; o < 64; o <<= 1) {
    int v = __shfl_up(incl, o);
    if (lane >= o) incl += v;
  }
  __shared__ int wsum[16];
  if (lane == 63) wsum[wid] = incl;
  __syncthreads();
  if (t < 16) {
    int iv = wsum[t];
    for (int o = 1; o < 16; o <<= 1) {
      int u = __shfl_up(iv, o);
      if (t >= o) iv += u;
    }
    wsum[t] = iv;
  }
  __syncthreads();
  int waveoff = (wid == 0) ? 0 : wsum[wid-1];
  int excl = waveoff + incl - local;   // pairs among rows < r0
  g_cnt[r0] = excl;
  g_cnt[r1] = excl + h0;
  if (h0) { g_ii[excl]      = r0; g_jj[excl]      = f0; }
  if (h1) { g_ii[excl + h0] = r1; g_jj[excl + h0] = f1; }
  if (t == 1023) g_K = waveoff + incl;
}

// term1 folded frame records computed directly from coords (no aug buffers)
__global__ void k_augfr(const float* __restrict__ coor,
                        const float* __restrict__ target) {
  int idx = blockIdx.x*blockDim.x + threadIdx.x;
  float xp[9], xt[9];
  int pos;
  if (idx < LL) {
    pos = idx + g_cnt[idx];
    #pragma unroll
    for (int c = 0; c < 9; ++c) { xp[c] = coor[idx*9+c]; xt[c] = target[idx*9+c]; }
  } else {
    int k = idx - LL;
    if (k >= g_K) return;
    int a = g_ii[k], b = g_jj[k];
    pos = a + k + 1;
    #pragma unroll
    for (int c = 0; c < 9; ++c) {
      xp[c] = 0.5f*(coor[a*9+c]   + coor[b*9+c]);
      xt[c] = 0.5f*(target[a*9+c] + target[b*9+c]);
    }
  }
  float A[9], tp[3], B[9], tt[3];
  rigid3(xp, A, tp);
  rigid3(xt, B, tt);
  packfr12(g_frames + (size_t)(LL + pos)*12, A, tp, B, tt);
}

// fused FAPE — measured best (34.7 us total, reproduced R7/R15): NP=8 points
// per thread in VGPRs, FPB=16 frames via wave-uniform global float4 loads
// (-> s_load, SGPRs), #pragma unroll 2, launch_bounds(256,4). Separate
// k_final (R14: fused threadfence+done-atomic tail costs ~5-7 us); separate
// k_augfr (R17: single-block fusion costs ~3.5 us).
__global__ void __launch_bounds__(256, 4) k_fape() {
  int Ftot = 2*LL + g_K;
  int f0 = blockIdx.y * FPB;
  if (f0 >= Ftot) return;
  int nf = min(FPB, Ftot - f0);
  int term1 = (f0 >= LL) ? 1 : 0;
  float clampv = term1 ? 5.f : 40.f;
  int t = threadIdx.x;

  int pbase = blockIdx.x*(256*NP) + t;   // grid.x * 256 * NP == PP exactly
  const float4* pt4 = reinterpret_cast<const float4*>(g_pts);
  float px[NP], py[NP], pz[NP], ttx[NP], tty[NP], ttz[NP];
  #pragma unroll
  for (int k = 0; k < NP; ++k) {
    int p = pbase + k*256;
    float4 a = pt4[p*2+0];
    float4 b = pt4[p*2+1];
    px[k] = a.x; py[k] = a.y; pz[k] = a.z;
    ttx[k] = a.w; tty[k] = b.x; ttz[k] = b.y;
  }
  float acc = 0.f;

  // wave-uniform frame pointer: compiler promotes to scalar loads (SGPRs)
  const float4* fr4 = reinterpret_cast<const float4*>(g_frames) + (size_t)f0*3;
  #pragma unroll 2
  for (int q = 0; q < nf; ++q) {
    float4 w0 = fr4[q*3+0];   // M00 M01 M02 M10
    float4 w1 = fr4[q*3+1];   // M11 M12 M20 M21
    float4 w2 = fr4[q*3+2];   // M22 d0  d1  d2
    #pragma unroll
    for (int k = 0; k < NP; ++k) {
      float m0 = fmaf(w0.x, ttx[k], fmaf(w0.y, tty[k], fmaf(w0.z, ttz[k], w2.y)));
      float m1 = fmaf(w0.w, ttx[k], fmaf(w1.x, tty[k], fmaf(w1.y, ttz[k], w2.z)));
      float m2 = fmaf(w1.z, ttx[k], fmaf(w1.w, tty[k], fmaf(w2.x, ttz[k], w2.w)));
      float dx = px[k] - m0, dy = py[k] - m1, dz = pz[k] - m2;
      float ss = fmaf(dx, dx, fmaf(dy, dy, fmaf(dz, dz, 0.001f)));
      acc += fminf(__builtin_amdgcn_sqrtf(ss), clampv);
    }
  }

  for (int o = 32; o >= 1; o >>= 1) acc += __shfl_down(acc, o);
  __shared__ float w[4];
  int lane = t & 63, wid = t >> 6;
  if (lane == 0) w[wid] = acc;
  __syncthreads();
  if (t == 0) {
    double s = (double)w[0] + (double)w[1] + (double)w[2] + (double)w[3];
    atomicAdd(&g_sum[term1], s);
  }
}

__global__ void k_final(float* __restrict__ out) {
  int K = g_K;
  double fape = g_sum[0] / ((double)LL * (double)PP);
  double r;
  if (K == 0) {
    r = fape / 10.0;
  } else {
    double fp = g_sum[1] / ((double)(LL + K) * (double)PP);
    r = (fape + fp) / 10.0;
  }
  out[0] = (float)r;
}

extern "C" void kernel_launch(void* const* d_in, const int* in_sizes, int n_in,
                              void* d_out, int out_size, void* d_ws, size_t ws_size,
                              hipStream_t stream) {
  const float* coor   = (const float*)d_in[0];
  const float* prot   = (const float*)d_in[1];
  const float* ptran  = (const float*)d_in[2];
  const float* target = (const float*)d_in[3];
  const int*   matrix = (const int*)d_in[4];
  float* out = (float*)d_out;

  k_prep<<<LL + 8 + PP/256, 256, 0, stream>>>((const int4*)matrix, coor, target, prot, ptran);
  k_scan<<<1, 1024, 0, stream>>>();
  k_augfr<<<16, 256, 0, stream>>>(coor, target);
  dim3 grid(PP/(256*NP), (3*LL)/FPB);   // 3 x 384 = 1152 blocks (864 active)
  k_fape<<<grid, 256, 0, stream>>>();
  k_final<<<1, 1, 0, stream>>>(out);
}